// Round 6
// baseline (326.526 us; speedup 1.0000x reference)
//
#include <hip/hip_runtime.h>
#include <hip/hip_fp16.h>

#define N_USERS 100000
#define M_ITEMS 50000
#define NNODES  (N_USERS + M_ITEMS)
#define EMBED   64
#define BATCH   8192

#define NU_E ((size_t)N_USERS * EMBED)
#define NE   ((size_t)NNODES * EMBED)    // 9,600,000 elements

#define SBN    512                        // nodes per super-bucket
#define NSB    ((NNODES + SBN - 1) / SBN) // 293
#define CAP    14336                      // edge slots per SB
#define CSTR   16                         // cursor padding stride (ints)
#define PBLK   512                        // partition blocks
#define PTILE  4688                       // edges per block
#define PRED_BLOCKS ((BATCH * 64) / 256)  // 2048
#define MAXU   8192                       // max distinct batch users
#define MAXI   16384                      // max distinct batch items
#define NLSLOT (MAXU + MAXI)              // 24576 list slots
#define CBLK   37                         // compaction blocks (37*4096 >= NNODES)

typedef unsigned int uint;

static __device__ __forceinline__ ushort f2bf(float f) {
    uint u = __float_as_uint(f);
    return (ushort)((u + 0x7fffu + ((u >> 16) & 1u)) >> 16);
}
static __device__ __forceinline__ float bf_lo(uint u) { return __uint_as_float(u << 16); }
static __device__ __forceinline__ float bf_hi(uint u) { return __uint_as_float(u & 0xffff0000u); }
static __device__ __forceinline__ float bfs(ushort u) { return __uint_as_float((uint)u << 16); }

// packed edge: dst (17 bits, bipartite-local) << 15 | fp16(val) sans sign (val in [0,1))
static __device__ __forceinline__ int packe(int d, int fbits) {
    ushort h = __half_as_ushort(__float2half(__int_as_float(fbits)));
    return (int)(((uint)d << 15) | (uint)(h & 0x7fffu));
}
static __device__ __forceinline__ float unp_val(int p) {
    return __half2float(__ushort_as_half((ushort)(p & 0x7fff)));
}

// ---------------------------------------------------------------------------
// Fused: block 0 = per-SB cursors to sb*CAP + zero compact counters;
//        block 1 = mark batch nodes (mark[] pre-zeroed via hipMemsetAsync);
//        blocks [2,..) = E0 = bf16(concat(eu0, ei0)).
// ---------------------------------------------------------------------------
__global__ void init_all(const float* __restrict__ eu, const float* __restrict__ ei,
                         ushort* __restrict__ E0, int* __restrict__ gcur,
                         int* __restrict__ cpt, char* __restrict__ mark,
                         const int* __restrict__ user, const int* __restrict__ item_i,
                         const int* __restrict__ item_j) {
    if (blockIdx.x == 0) {
        for (int i = threadIdx.x; i < NSB; i += 1024) gcur[i * CSTR] = i * CAP;
        if (threadIdx.x < 2) cpt[threadIdx.x] = 0;
        return;
    }
    if (blockIdx.x == 1) {
        for (int j = threadIdx.x; j < 3 * BATCH; j += 1024) {
            int which = j >> 13;           // 0:user 1:item_i 2:item_j
            int b = j & (BATCH - 1);
            int node = (which == 0) ? user[b]
                     : N_USERS + ((which == 1) ? item_i[b] : item_j[b]);
            mark[node] = 1;
        }
        return;
    }
    size_t t = (size_t)(blockIdx.x - 2) * 1024 + threadIdx.x;
    const size_t nu4 = NU_E / 4;
    const size_t n4  = NE / 4;
    if (t >= n4) return;
    float4 v = (t < nu4) ? ((const float4*)eu)[t] : ((const float4*)ei)[t - nu4];
    ((ushort4*)E0)[t] = make_ushort4(f2bf(v.x), f2bf(v.y), f2bf(v.z), f2bf(v.w));
}

// ---------------------------------------------------------------------------
// Partition: single LDS pass per block (PTILE edges), LDS counting sort by
// super-bucket (512 nodes), contiguous run write-out into CAP-padded SB
// regions via atomic run reservation.
// ebuf.x = (src & 511) | (dst_local << 9), ebuf.y = val fp32 bits
// ---------------------------------------------------------------------------
__global__ void __launch_bounds__(1024)
partition2(const int* __restrict__ src, const int* __restrict__ dst,
           const float* __restrict__ vals, int* __restrict__ gcur,
           int2* __restrict__ ebuf, int nnz) {
    __shared__ int2 data[PTILE];      // 37.5 KB
    __shared__ int  cnt[NSB];
    __shared__ int  cur[NSB];
    __shared__ int  lbeg[NSB];
    __shared__ int  gbase[NSB];
    __shared__ int  wsum[16];
    const int blk = blockIdx.x;
    const int tid = threadIdx.x;
    const int lane = tid & 63, w = tid >> 6;
    const int base = blk * PTILE;
    const int end  = min(base + PTILE, nnz);

    for (int i = tid; i < NSB; i += 1024) cnt[i] = 0;
    __syncthreads();
    for (int i = base + tid; i < end; i += 1024)
        atomicAdd(&cnt[src[i] >> 9], 1);
    __syncthreads();
    // ---- wave-shfl exclusive scan over cnt[0..NSB) ----
    int c = (tid < NSB) ? cnt[tid] : 0;
    int v = c;
    #pragma unroll
    for (int off = 1; off < 64; off <<= 1) {
        int t = __shfl_up(v, off);
        if (lane >= off) v += t;
    }
    if (lane == 63) wsum[w] = v;
    __syncthreads();
    int wpre = 0;
    #pragma unroll
    for (int k = 0; k < 16; ++k) wpre += (k < w) ? wsum[k] : 0;
    v += wpre;                                   // inclusive prefix
    if (tid < NSB) {
        int ex = v - c;
        cur[tid]  = ex;                          // mutable cursor
        lbeg[tid] = ex;                          // stable run start
        if (c > 0) gbase[tid] = atomicAdd(&gcur[tid * CSTR], c);
    }
    __syncthreads();
    for (int i = base + tid; i < end; i += 1024) {
        int sv = src[i];
        int d  = dst[i];
        float fv = vals[i];
        if (d >= N_USERS) d -= N_USERS;          // bipartite-local dst index
        int p = atomicAdd(&cur[sv >> 9], 1);
        data[p] = make_int2((sv & 511) | (d << 9), __float_as_int(fv));
    }
    __syncthreads();
    int grp = tid >> 4, lane16 = tid & 15;        // 64 groups of 16
    for (int b = grp; b < NSB; b += 64) {
        int cc = cnt[b];
        if (cc == 0) continue;
        int lb = lbeg[b];
        int gb = gbase[b];
        for (int j = lane16; j < cc; j += 16)
            ebuf[gb + j] = data[lb + j];
    }
}

// ---------------------------------------------------------------------------
// Blocks [0,NSB): per-SB node counts + shfl scan -> offs2 {start,deg}; direct
// global scatter of packed 4 B edges (SB region L2-resident); descending perm.
// Blocks [NSB,NSB+CBLK): compact marked nodes -> nlist (users front, items
// at offset MAXU), counters in cpt[0]/cpt[1].
// ---------------------------------------------------------------------------
__global__ void __launch_bounds__(1024)
sb_sort(const int* __restrict__ gcur, const int2* __restrict__ ebuf,
        int2* __restrict__ offs2, int* __restrict__ ep,
        int* __restrict__ perm,
        const char* __restrict__ mark, int* __restrict__ nlist,
        int* __restrict__ cpt) {
    int tid = threadIdx.x;
    if (blockIdx.x >= NSB) {
        int cb = blockIdx.x - NSB;
        #pragma unroll
        for (int j = 0; j < 4; ++j) {
            int i = cb * 4096 + j * 1024 + tid;
            if (i < NNODES && mark[i]) {
                if (i < N_USERS) {
                    int p = atomicAdd(&cpt[0], 1);
                    nlist[p] = i;
                } else {
                    int p = atomicAdd(&cpt[1], 1);
                    nlist[MAXU + p] = i;
                }
            }
        }
        return;
    }
    __shared__ int cnt[SBN], cur[SBN], bcnt[256];
    __shared__ int wsum[16];
    int sb  = blockIdx.x;
    int lane = tid & 63, w = tid >> 6;
    int beg = sb * CAP;
    int end = gcur[sb * CSTR];        // = beg + sb_len after partition
    if (tid < SBN) cnt[tid] = 0;
    __syncthreads();
    for (int i = beg + tid; i < end; i += 1024)
        atomicAdd(&cnt[ebuf[i].x & (SBN - 1)], 1);
    __syncthreads();
    // ---- wave-shfl scan over cnt[0..512) ----
    int c = (tid < SBN) ? cnt[tid] : 0;
    int v = c;
    #pragma unroll
    for (int off = 1; off < 64; off <<= 1) {
        int t = __shfl_up(v, off);
        if (lane >= off) v += t;
    }
    if (lane == 63) wsum[w] = v;
    __syncthreads();
    if (tid < SBN) {
        int wpre = 0;
        #pragma unroll
        for (int k = 0; k < 8; ++k) wpre += (k < w) ? wsum[k] : 0;
        v += wpre;
        int lbase = v - c;                         // exclusive
        int node = sb * SBN + tid;
        if (node < NNODES) offs2[node] = make_int2(beg + lbase, c);
        cur[tid] = lbase;
    }
    __syncthreads();
    // ---- direct scatter to ep (region L2-resident on this XCD) ----
    for (int i = beg + tid; i < end; i += 1024) {
        int2 e = ebuf[i];
        int p = atomicAdd(&cur[e.x & (SBN - 1)], 1);
        ep[beg + p] = packe(e.x >> 9, e.y);
    }
    // ---- perm: counting sort by DESCENDING degree ----
    __syncthreads();
    if (tid < 256) bcnt[tid] = 0;
    __syncthreads();
    int nodeCount = min(NNODES - sb * SBN, SBN);
    int bin = 0;
    if (tid < nodeCount) {
        bin = 255 - min(cnt[tid], 255);            // descending order
        atomicAdd(&bcnt[bin], 1);
    }
    __syncthreads();
    int c2 = (tid < 256) ? bcnt[tid] : 0;
    int v2 = c2;
    #pragma unroll
    for (int off = 1; off < 64; off <<= 1) {
        int t = __shfl_up(v2, off);
        if (lane >= off) v2 += t;
    }
    if (tid < 256 && lane == 63) wsum[w] = v2;
    __syncthreads();
    if (tid < 256) {
        int wpre = 0;
        #pragma unroll
        for (int k = 0; k < 4; ++k) wpre += (k < w) ? wsum[k] : 0;
        v2 += wpre;
        cur[tid] = sb * SBN + (v2 - c2);
    }
    __syncthreads();
    if (tid < nodeCount) {
        int rank = atomicAdd(&cur[bin], 1);
        perm[rank] = sb * SBN + tid;
    }
}

// ---------------------------------------------------------------------------
// Gather layer (UNCHANGED control group): Enext[node] = sum val * Eprev[dst]
// 8 nodes/wave (degree-sorted desc), 8 lanes/node, branch-free unroll-16.
// ---------------------------------------------------------------------------
__global__ void gather_E(const int2* __restrict__ offs2, const int* __restrict__ ep,
                         const int* __restrict__ perm,
                         const ushort* __restrict__ Eprev, ushort* __restrict__ Enext) {
    int t = blockIdx.x * blockDim.x + threadIdx.x;
    int wave = t >> 6;
    int lane = t & 63;
    int g = lane >> 3;
    int q = lane & 7;
    int ln = wave * 8 + g;
    bool valid = ln < NNODES;
    int node = valid ? perm[ln] : 0;
    int2 od = valid ? offs2[node] : make_int2(0, 0);
    int start = od.x;
    int deg   = od.y;
    const uint4* other = (const uint4*)(Eprev + (node < N_USERS ? NU_E : 0));
    int lastIdx = max(start + deg - 1, 0);

    int md = deg;
    #pragma unroll
    for (int off = 8; off <= 32; off <<= 1) md = max(md, __shfl_xor(md, off));

    float a0=0.f,a1=0.f,a2=0.f,a3=0.f,a4=0.f,a5=0.f,a6=0.f,a7=0.f;
    for (int k = 0; k < md; k += 16) {
        int e[16];
        uint4 r[16];
        #pragma unroll
        for (int c = 0; c < 16; ++c) {
            int idx = (k + c < deg) ? start + k + c : lastIdx;
            e[c] = ep[idx];
            if (k + c >= deg) e[c] = 0;           // dst=0 (hot line), val=+0.0
        }
        #pragma unroll
        for (int c = 0; c < 16; ++c)
            r[c] = other[(size_t)(((uint)e[c]) >> 15) * 8 + q];
        #pragma unroll
        for (int c = 0; c < 16; ++c) {
            float v = unp_val(e[c]);
            a0 = fmaf(v, bf_lo(r[c].x), a0);  a1 = fmaf(v, bf_hi(r[c].x), a1);
            a2 = fmaf(v, bf_lo(r[c].y), a2);  a3 = fmaf(v, bf_hi(r[c].y), a3);
            a4 = fmaf(v, bf_lo(r[c].z), a4);  a5 = fmaf(v, bf_hi(r[c].z), a5);
            a6 = fmaf(v, bf_lo(r[c].w), a6);  a7 = fmaf(v, bf_hi(r[c].w), a7);
        }
    }

    if (!valid) return;
    uint4 o;
    o.x = (uint)f2bf(a0) | ((uint)f2bf(a1) << 16);
    o.y = (uint)f2bf(a2) | ((uint)f2bf(a3) << 16);
    o.z = (uint)f2bf(a4) | ((uint)f2bf(a5) << 16);
    o.w = (uint)f2bf(a6) | ((uint)f2bf(a7) << 16);
    ((uint4*)Enext)[(size_t)node * 8 + q] = o;
}

// ---------------------------------------------------------------------------
// Layer-3 gather over the COMPACTED batch-node lists only (~21K of 150K
// nodes, ~19% of edges). Same proven body; node selection from nlist.
// Slots [0,MAXU) = users (valid < cpt[0]); [MAXU,MAXU+MAXI) = items.
// ---------------------------------------------------------------------------
__global__ void gather_E_list(const int2* __restrict__ offs2, const int* __restrict__ ep,
                              const int* __restrict__ nlist, const int* __restrict__ cpt,
                              const ushort* __restrict__ Eprev, ushort* __restrict__ Enext) {
    int t = blockIdx.x * blockDim.x + threadIdx.x;
    int wave = t >> 6;
    int lane = t & 63;
    int g = lane >> 3;
    int q = lane & 7;
    int ln = wave * 8 + g;
    int cntU = cpt[0], cntI = cpt[1];
    bool isU = ln < MAXU;
    int li = isU ? ln : ln - MAXU;
    bool valid = li < (isU ? cntU : cntI);
    int node = valid ? nlist[(isU ? 0 : MAXU) + li] : 0;
    int2 od = valid ? offs2[node] : make_int2(0, 0);
    int start = od.x;
    int deg   = od.y;
    const uint4* other = (const uint4*)(Eprev + (node < N_USERS ? NU_E : 0));
    int lastIdx = max(start + deg - 1, 0);

    int md = deg;
    #pragma unroll
    for (int off = 8; off <= 32; off <<= 1) md = max(md, __shfl_xor(md, off));

    float a0=0.f,a1=0.f,a2=0.f,a3=0.f,a4=0.f,a5=0.f,a6=0.f,a7=0.f;
    for (int k = 0; k < md; k += 16) {
        int e[16];
        uint4 r[16];
        #pragma unroll
        for (int c = 0; c < 16; ++c) {
            int idx = (k + c < deg) ? start + k + c : lastIdx;
            e[c] = ep[idx];
            if (k + c >= deg) e[c] = 0;
        }
        #pragma unroll
        for (int c = 0; c < 16; ++c)
            r[c] = other[(size_t)(((uint)e[c]) >> 15) * 8 + q];
        #pragma unroll
        for (int c = 0; c < 16; ++c) {
            float v = unp_val(e[c]);
            a0 = fmaf(v, bf_lo(r[c].x), a0);  a1 = fmaf(v, bf_hi(r[c].x), a1);
            a2 = fmaf(v, bf_lo(r[c].y), a2);  a3 = fmaf(v, bf_hi(r[c].y), a3);
            a4 = fmaf(v, bf_lo(r[c].z), a4);  a5 = fmaf(v, bf_hi(r[c].z), a5);
            a6 = fmaf(v, bf_lo(r[c].w), a6);  a7 = fmaf(v, bf_hi(r[c].w), a7);
        }
    }

    if (!valid) return;
    uint4 o;
    o.x = (uint)f2bf(a0) | ((uint)f2bf(a1) << 16);
    o.y = (uint)f2bf(a2) | ((uint)f2bf(a3) << 16);
    o.z = (uint)f2bf(a4) | ((uint)f2bf(a5) << 16);
    o.w = (uint)f2bf(a6) | ((uint)f2bf(a7) << 16);
    ((uint4*)Enext)[(size_t)node * 8 + q] = o;
}

// ---------------------------------------------------------------------------
// Predict: sum 4 generations of bf16 rows, dot, /16; reg-loss block partials.
// ---------------------------------------------------------------------------
__global__ void predict_kernel(const int* __restrict__ user, const int* __restrict__ item_i,
                               const int* __restrict__ item_j,
                               const ushort* __restrict__ E0, const ushort* __restrict__ E1,
                               const ushort* __restrict__ E2, const ushort* __restrict__ E3,
                               const float* __restrict__ eu0, const float* __restrict__ ei0,
                               float* __restrict__ out, float* __restrict__ rbuf) {
    __shared__ float rpart[4];
    int t = blockIdx.x * blockDim.x + threadIdx.x;
    int b = t >> 6;
    int d = t & 63;
    int wv = threadIdx.x >> 6;
    float pi = 0.f, pj = 0.f, r = 0.f;
    if (b < BATCH) {
        size_t ru = (size_t)user[b] * EMBED + d;
        size_t ri = ((size_t)N_USERS + item_i[b]) * EMBED + d;
        size_t rj = ((size_t)N_USERS + item_j[b]) * EMBED + d;
        float ue = bfs(E0[ru]) + bfs(E1[ru]) + bfs(E2[ru]) + bfs(E3[ru]);
        float ie = bfs(E0[ri]) + bfs(E1[ri]) + bfs(E2[ri]) + bfs(E3[ri]);
        float je = bfs(E0[rj]) + bfs(E1[rj]) + bfs(E2[rj]) + bfs(E3[rj]);
        pi = ue * ie;
        pj = ue * je;
        float u0 = eu0[(size_t)user[b] * EMBED + d];
        float i0 = ei0[(size_t)item_i[b] * EMBED + d];
        float j0 = ei0[(size_t)item_j[b] * EMBED + d];
        r = u0 * u0 + i0 * i0 + j0 * j0;
    }
    #pragma unroll
    for (int off = 32; off > 0; off >>= 1) {
        pi += __shfl_down(pi, off);
        pj += __shfl_down(pj, off);
        r  += __shfl_down(r,  off);
    }
    if (d == 0 && b < BATCH) {
        out[b]         = pi * (1.0f / 16.0f);
        out[BATCH + b] = pj * (1.0f / 16.0f);
        rpart[wv] = r;
    }
    __syncthreads();
    if (threadIdx.x == 0)
        rbuf[blockIdx.x] = rpart[0] + rpart[1] + rpart[2] + rpart[3];
}

__global__ void finalize_reg(const float* __restrict__ rbuf, float* __restrict__ out) {
    __shared__ float lds[4];
    int tid = threadIdx.x;
    float s = 0.f;
    for (int i = tid; i < PRED_BLOCKS; i += 256) s += rbuf[i];
    #pragma unroll
    for (int off = 32; off > 0; off >>= 1) s += __shfl_down(s, off);
    if ((tid & 63) == 0) lds[tid >> 6] = s;
    __syncthreads();
    if (tid == 0)
        out[2 * BATCH] = (lds[0] + lds[1] + lds[2] + lds[3]) * (0.5f / (float)BATCH);
}

// ---------------------------------------------------------------------------
extern "C" void kernel_launch(void* const* d_in, const int* in_sizes, int n_in,
                              void* d_out, int out_size, void* d_ws, size_t ws_size,
                              hipStream_t stream) {
    const int*   user      = (const int*)  d_in[0];
    const int*   item_i    = (const int*)  d_in[1];
    const int*   item_j    = (const int*)  d_in[2];
    const int*   edge_src  = (const int*)  d_in[5];
    const int*   edge_dst  = (const int*)  d_in[6];
    const float* edge_vals = (const float*)d_in[7];
    const float* eu0       = (const float*)d_in[8];
    const float* ei0       = (const float*)d_in[9];
    const int    nnz       = in_sizes[5];

    float* out = (float*)d_out;

    // ---- workspace (~96 MB) ----
    ushort* E0    = (ushort*)d_ws;               // 19.2 MB each
    ushort* E1    = E0 + NE;
    ushort* E2    = E1 + NE;
    ushort* E3    = E2 + NE;
    int*    ep    = (int*)(E3 + NE);             // NSB*CAP packed edges, 16.8 MB
    int2*   offs2 = (int2*)(ep + (size_t)NSB * CAP); // {start, deg} per node
    int*    gcur  = (int*)(offs2 + NNODES);      // NSB padded cursors (1/line)
    int*    perm  = gcur + NSB * CSTR;           // NNODES
    float*  rbuf  = (float*)(perm + NNODES);     // PRED_BLOCKS
    int*    nlist = (int*)(rbuf + PRED_BLOCKS);  // NLSLOT batch-node list
    int*    cpt   = nlist + NLSLOT;              // 2 compact counters
    char*   mark  = (char*)(cpt + 16);           // NNODES bytes
    // ebuf = NSB*CAP int2 = 33.6 MB: spans E1..E2; dead before gathers write them
    int2*   ebuf  = (int2*)E1;

    const int initBlocks = (int)((NE / 4 + 1023) / 1024);   // 2344

    // 0) zero the batch-node mark array (stream-ordered, graph-capturable)
    hipMemsetAsync(mark, 0, NNODES, stream);
    // 1) fused cursor-init + batch-node marking + E0 = bf16(concat)
    init_all<<<2 + initBlocks, 1024, 0, stream>>>(eu0, ei0, E0, gcur, cpt, mark,
                                                  user, item_i, item_j);
    // 2) single-pass LDS partition into CAP-padded SB runs (atomic reserve)
    partition2<<<PBLK, 1024, 0, stream>>>(edge_src, edge_dst, edge_vals,
                                          gcur, ebuf, nnz);
    // 3) per-SB node sort (offs2/ep/perm) + batch-node list compaction
    sb_sort<<<NSB + CBLK, 1024, 0, stream>>>(gcur, ebuf, offs2, ep, perm,
                                             mark, nlist, cpt);
    // 4-5) full propagation layers 1-2
    const int gblocks = (int)((((NNODES + 7) / 8) * 64 + 255) / 256);
    gather_E<<<gblocks, 256, 0, stream>>>(offs2, ep, perm, E0, E1);
    gather_E<<<gblocks, 256, 0, stream>>>(offs2, ep, perm, E1, E2);
    // 6) layer 3 pruned to batch nodes only (~19% of edges)
    const int lblocks = (NLSLOT / 8 * 64) / 256;   // 768
    gather_E_list<<<lblocks, 256, 0, stream>>>(offs2, ep, nlist, cpt, E2, E3);
    // 7-8) predictions + reg loss
    predict_kernel<<<PRED_BLOCKS, 256, 0, stream>>>(
        user, item_i, item_j, E0, E1, E2, E3, eu0, ei0, out, rbuf);
    finalize_reg<<<1, 256, 0, stream>>>(rbuf, out);
}

// Round 7
// 274.549 us; speedup vs baseline: 1.1893x; 1.1893x over previous
//
#include <hip/hip_runtime.h>
#include <hip/hip_fp16.h>

#define N_USERS 100000
#define M_ITEMS 50000
#define NNODES  (N_USERS + M_ITEMS)
#define EMBED   64
#define BATCH   8192

#define NU_E ((size_t)N_USERS * EMBED)
#define NE   ((size_t)NNODES * EMBED)    // 9,600,000 elements

#define SBN    512                        // nodes per super-bucket
#define NSB    ((NNODES + SBN - 1) / SBN) // 293
#define CAP    14336                      // edge slots per SB
#define CSTR   16                         // cursor padding stride (ints)
#define PBLK   512                        // partition blocks
#define PTILE  4688                       // edges per block
#define PRED_BLOCKS ((BATCH * 64) / 256)  // 2048

typedef unsigned int uint;

static __device__ __forceinline__ ushort f2bf(float f) {
    uint u = __float_as_uint(f);
    return (ushort)((u + 0x7fffu + ((u >> 16) & 1u)) >> 16);
}
static __device__ __forceinline__ float bf_lo(uint u) { return __uint_as_float(u << 16); }
static __device__ __forceinline__ float bf_hi(uint u) { return __uint_as_float(u & 0xffff0000u); }
static __device__ __forceinline__ float bfs(ushort u) { return __uint_as_float((uint)u << 16); }

// packed edge: dst (17 bits, bipartite-local) << 15 | fp16(val) sans sign (val in [0,1))
static __device__ __forceinline__ int packe(int d, int fbits) {
    ushort h = __half_as_ushort(__float2half(__int_as_float(fbits)));
    return (int)(((uint)d << 15) | (uint)(h & 0x7fffu));
}
static __device__ __forceinline__ float unp_val(int p) {
    return __half2float(__ushort_as_half((ushort)(p & 0x7fff)));
}

// ---------------------------------------------------------------------------
// Fused: block 0 inits per-SB global cursors to sb*CAP;
//        blocks [1,..) = E0 = bf16(concat(eu0, ei0)).   (exact round-5 form)
// ---------------------------------------------------------------------------
__global__ void init_all(const float* __restrict__ eu, const float* __restrict__ ei,
                         ushort* __restrict__ E0, int* __restrict__ gcur) {
    if (blockIdx.x == 0) {
        for (int i = threadIdx.x; i < NSB; i += 1024) gcur[i * CSTR] = i * CAP;
        return;
    }
    size_t t = (size_t)(blockIdx.x - 1) * 1024 + threadIdx.x;
    const size_t nu4 = NU_E / 4;
    const size_t n4  = NE / 4;
    if (t >= n4) return;
    float4 v = (t < nu4) ? ((const float4*)eu)[t] : ((const float4*)ei)[t - nu4];
    ((ushort4*)E0)[t] = make_ushort4(f2bf(v.x), f2bf(v.y), f2bf(v.z), f2bf(v.w));
}

// ---------------------------------------------------------------------------
// Partition: single LDS pass per block (PTILE edges), LDS counting sort by
// super-bucket (512 nodes), contiguous run write-out into CAP-padded SB
// regions via atomic run reservation.   (exact round-5 form)
// ebuf.x = (src & 511) | (dst_local << 9), ebuf.y = val fp32 bits
// ---------------------------------------------------------------------------
__global__ void __launch_bounds__(1024)
partition2(const int* __restrict__ src, const int* __restrict__ dst,
           const float* __restrict__ vals, int* __restrict__ gcur,
           int2* __restrict__ ebuf, int nnz) {
    __shared__ int2 data[PTILE];      // 37.5 KB
    __shared__ int  cnt[NSB];
    __shared__ int  cur[NSB];
    __shared__ int  lbeg[NSB];
    __shared__ int  gbase[NSB];
    __shared__ int  wsum[16];
    const int blk = blockIdx.x;
    const int tid = threadIdx.x;
    const int lane = tid & 63, w = tid >> 6;
    const int base = blk * PTILE;
    const int end  = min(base + PTILE, nnz);

    for (int i = tid; i < NSB; i += 1024) cnt[i] = 0;
    __syncthreads();
    for (int i = base + tid; i < end; i += 1024)
        atomicAdd(&cnt[src[i] >> 9], 1);
    __syncthreads();
    // ---- wave-shfl exclusive scan over cnt[0..NSB) ----
    int c = (tid < NSB) ? cnt[tid] : 0;
    int v = c;
    #pragma unroll
    for (int off = 1; off < 64; off <<= 1) {
        int t = __shfl_up(v, off);
        if (lane >= off) v += t;
    }
    if (lane == 63) wsum[w] = v;
    __syncthreads();
    int wpre = 0;
    #pragma unroll
    for (int k = 0; k < 16; ++k) wpre += (k < w) ? wsum[k] : 0;
    v += wpre;                                   // inclusive prefix
    if (tid < NSB) {
        int ex = v - c;
        cur[tid]  = ex;                          // mutable cursor
        lbeg[tid] = ex;                          // stable run start
        if (c > 0) gbase[tid] = atomicAdd(&gcur[tid * CSTR], c);
    }
    __syncthreads();
    for (int i = base + tid; i < end; i += 1024) {
        int sv = src[i];
        int d  = dst[i];
        float fv = vals[i];
        if (d >= N_USERS) d -= N_USERS;          // bipartite-local dst index
        int p = atomicAdd(&cur[sv >> 9], 1);
        data[p] = make_int2((sv & 511) | (d << 9), __float_as_int(fv));
    }
    __syncthreads();
    int grp = tid >> 4, lane16 = tid & 15;        // 64 groups of 16
    for (int b = grp; b < NSB; b += 64) {
        int cc = cnt[b];
        if (cc == 0) continue;
        int lb = lbeg[b];
        int gb = gbase[b];
        for (int j = lane16; j < cc; j += 16)
            ebuf[gb + j] = data[lb + j];
    }
}

// ---------------------------------------------------------------------------
// One block per super-bucket: LDS node counts + wave-shfl scan -> offs2
// {start,deg}; direct global scatter of packed 4 B edges (SB region
// L2-resident); descending-degree perm.   (exact round-5 form)
// ---------------------------------------------------------------------------
__global__ void __launch_bounds__(1024)
sb_sort(const int* __restrict__ gcur, const int2* __restrict__ ebuf,
        int2* __restrict__ offs2, int* __restrict__ ep,
        int* __restrict__ perm) {
    __shared__ int cnt[SBN], cur[SBN], bcnt[256];
    __shared__ int wsum[16];
    int sb  = blockIdx.x;
    int tid = threadIdx.x;
    int lane = tid & 63, w = tid >> 6;
    int beg = sb * CAP;
    int end = gcur[sb * CSTR];        // = beg + sb_len after partition
    if (tid < SBN) cnt[tid] = 0;
    __syncthreads();
    for (int i = beg + tid; i < end; i += 1024)
        atomicAdd(&cnt[ebuf[i].x & (SBN - 1)], 1);
    __syncthreads();
    // ---- wave-shfl scan over cnt[0..512) ----
    int c = (tid < SBN) ? cnt[tid] : 0;
    int v = c;
    #pragma unroll
    for (int off = 1; off < 64; off <<= 1) {
        int t = __shfl_up(v, off);
        if (lane >= off) v += t;
    }
    if (lane == 63) wsum[w] = v;
    __syncthreads();
    if (tid < SBN) {
        int wpre = 0;
        #pragma unroll
        for (int k = 0; k < 8; ++k) wpre += (k < w) ? wsum[k] : 0;
        v += wpre;
        int lbase = v - c;                         // exclusive
        int node = sb * SBN + tid;
        if (node < NNODES) offs2[node] = make_int2(beg + lbase, c);
        cur[tid] = lbase;
    }
    __syncthreads();
    // ---- direct scatter to ep (region L2-resident on this XCD) ----
    for (int i = beg + tid; i < end; i += 1024) {
        int2 e = ebuf[i];
        int p = atomicAdd(&cur[e.x & (SBN - 1)], 1);
        ep[beg + p] = packe(e.x >> 9, e.y);
    }
    // ---- perm: counting sort by DESCENDING degree ----
    __syncthreads();
    if (tid < 256) bcnt[tid] = 0;
    __syncthreads();
    int nodeCount = min(NNODES - sb * SBN, SBN);
    int bin = 0;
    if (tid < nodeCount) {
        bin = 255 - min(cnt[tid], 255);            // descending order
        atomicAdd(&bcnt[bin], 1);
    }
    __syncthreads();
    int c2 = (tid < 256) ? bcnt[tid] : 0;
    int v2 = c2;
    #pragma unroll
    for (int off = 1; off < 64; off <<= 1) {
        int t = __shfl_up(v2, off);
        if (lane >= off) v2 += t;
    }
    if (tid < 256 && lane == 63) wsum[w] = v2;
    __syncthreads();
    if (tid < 256) {
        int wpre = 0;
        #pragma unroll
        for (int k = 0; k < 4; ++k) wpre += (k < w) ? wsum[k] : 0;
        v2 += wpre;
        cur[tid] = sb * SBN + (v2 - c2);
    }
    __syncthreads();
    if (tid < nodeCount) {
        int rank = atomicAdd(&cur[bin], 1);
        perm[rank] = sb * SBN + tid;
    }
}

// ---------------------------------------------------------------------------
// Gather layer (UNCHANGED control group): Enext[node] = sum val * Eprev[dst]
// 8 nodes/wave (degree-sorted desc), 8 lanes/node, branch-free unroll-16.
// ---------------------------------------------------------------------------
__global__ void gather_E(const int2* __restrict__ offs2, const int* __restrict__ ep,
                         const int* __restrict__ perm,
                         const ushort* __restrict__ Eprev, ushort* __restrict__ Enext) {
    int t = blockIdx.x * blockDim.x + threadIdx.x;
    int wave = t >> 6;
    int lane = t & 63;
    int g = lane >> 3;
    int q = lane & 7;
    int ln = wave * 8 + g;
    bool valid = ln < NNODES;
    int node = valid ? perm[ln] : 0;
    int2 od = valid ? offs2[node] : make_int2(0, 0);
    int start = od.x;
    int deg   = od.y;
    const uint4* other = (const uint4*)(Eprev + (node < N_USERS ? NU_E : 0));
    int lastIdx = max(start + deg - 1, 0);

    int md = deg;
    #pragma unroll
    for (int off = 8; off <= 32; off <<= 1) md = max(md, __shfl_xor(md, off));

    float a0=0.f,a1=0.f,a2=0.f,a3=0.f,a4=0.f,a5=0.f,a6=0.f,a7=0.f;
    for (int k = 0; k < md; k += 16) {
        int e[16];
        uint4 r[16];
        #pragma unroll
        for (int c = 0; c < 16; ++c) {
            int idx = (k + c < deg) ? start + k + c : lastIdx;
            e[c] = ep[idx];
            if (k + c >= deg) e[c] = 0;           // dst=0 (hot line), val=+0.0
        }
        #pragma unroll
        for (int c = 0; c < 16; ++c)
            r[c] = other[(size_t)(((uint)e[c]) >> 15) * 8 + q];
        #pragma unroll
        for (int c = 0; c < 16; ++c) {
            float v = unp_val(e[c]);
            a0 = fmaf(v, bf_lo(r[c].x), a0);  a1 = fmaf(v, bf_hi(r[c].x), a1);
            a2 = fmaf(v, bf_lo(r[c].y), a2);  a3 = fmaf(v, bf_hi(r[c].y), a3);
            a4 = fmaf(v, bf_lo(r[c].z), a4);  a5 = fmaf(v, bf_hi(r[c].z), a5);
            a6 = fmaf(v, bf_lo(r[c].w), a6);  a7 = fmaf(v, bf_hi(r[c].w), a7);
        }
    }

    if (!valid) return;
    uint4 o;
    o.x = (uint)f2bf(a0) | ((uint)f2bf(a1) << 16);
    o.y = (uint)f2bf(a2) | ((uint)f2bf(a3) << 16);
    o.z = (uint)f2bf(a4) | ((uint)f2bf(a5) << 16);
    o.w = (uint)f2bf(a6) | ((uint)f2bf(a7) << 16);
    ((uint4*)Enext)[(size_t)node * 8 + q] = o;
}

// ---------------------------------------------------------------------------
// Layer-3 gather DIRECTLY over the batch index arrays (no dedup; recomputing
// a node twice writes byte-identical values -> benign race). Slot ln:
// [0,B) -> user[ln]; [B,2B) -> item_i; [2B,3B) -> item_j. All slots valid.
// ---------------------------------------------------------------------------
__global__ void gather_E_list(const int2* __restrict__ offs2, const int* __restrict__ ep,
                              const int* __restrict__ user, const int* __restrict__ item_i,
                              const int* __restrict__ item_j,
                              const ushort* __restrict__ Eprev, ushort* __restrict__ Enext) {
    int t = blockIdx.x * blockDim.x + threadIdx.x;
    int wave = t >> 6;
    int lane = t & 63;
    int g = lane >> 3;
    int q = lane & 7;
    int ln = wave * 8 + g;            // [0, 3*BATCH)
    int b = ln & (BATCH - 1);
    int which = ln >> 13;             // 0:user 1:item_i 2:item_j
    int node = (which == 0) ? user[b]
             : N_USERS + ((which == 1) ? item_i[b] : item_j[b]);
    int2 od = offs2[node];
    int start = od.x;
    int deg   = od.y;
    const uint4* other = (const uint4*)(Eprev + (node < N_USERS ? NU_E : 0));
    int lastIdx = max(start + deg - 1, 0);

    int md = deg;
    #pragma unroll
    for (int off = 8; off <= 32; off <<= 1) md = max(md, __shfl_xor(md, off));

    float a0=0.f,a1=0.f,a2=0.f,a3=0.f,a4=0.f,a5=0.f,a6=0.f,a7=0.f;
    for (int k = 0; k < md; k += 16) {
        int e[16];
        uint4 r[16];
        #pragma unroll
        for (int c = 0; c < 16; ++c) {
            int idx = (k + c < deg) ? start + k + c : lastIdx;
            e[c] = ep[idx];
            if (k + c >= deg) e[c] = 0;
        }
        #pragma unroll
        for (int c = 0; c < 16; ++c)
            r[c] = other[(size_t)(((uint)e[c]) >> 15) * 8 + q];
        #pragma unroll
        for (int c = 0; c < 16; ++c) {
            float v = unp_val(e[c]);
            a0 = fmaf(v, bf_lo(r[c].x), a0);  a1 = fmaf(v, bf_hi(r[c].x), a1);
            a2 = fmaf(v, bf_lo(r[c].y), a2);  a3 = fmaf(v, bf_hi(r[c].y), a3);
            a4 = fmaf(v, bf_lo(r[c].z), a4);  a5 = fmaf(v, bf_hi(r[c].z), a5);
            a6 = fmaf(v, bf_lo(r[c].w), a6);  a7 = fmaf(v, bf_hi(r[c].w), a7);
        }
    }

    uint4 o;
    o.x = (uint)f2bf(a0) | ((uint)f2bf(a1) << 16);
    o.y = (uint)f2bf(a2) | ((uint)f2bf(a3) << 16);
    o.z = (uint)f2bf(a4) | ((uint)f2bf(a5) << 16);
    o.w = (uint)f2bf(a6) | ((uint)f2bf(a7) << 16);
    ((uint4*)Enext)[(size_t)node * 8 + q] = o;
}

// ---------------------------------------------------------------------------
// Predict: sum 4 generations of bf16 rows, dot, /16; reg-loss block partials.
// ---------------------------------------------------------------------------
__global__ void predict_kernel(const int* __restrict__ user, const int* __restrict__ item_i,
                               const int* __restrict__ item_j,
                               const ushort* __restrict__ E0, const ushort* __restrict__ E1,
                               const ushort* __restrict__ E2, const ushort* __restrict__ E3,
                               const float* __restrict__ eu0, const float* __restrict__ ei0,
                               float* __restrict__ out, float* __restrict__ rbuf) {
    __shared__ float rpart[4];
    int t = blockIdx.x * blockDim.x + threadIdx.x;
    int b = t >> 6;
    int d = t & 63;
    int wv = threadIdx.x >> 6;
    float pi = 0.f, pj = 0.f, r = 0.f;
    if (b < BATCH) {
        size_t ru = (size_t)user[b] * EMBED + d;
        size_t ri = ((size_t)N_USERS + item_i[b]) * EMBED + d;
        size_t rj = ((size_t)N_USERS + item_j[b]) * EMBED + d;
        float ue = bfs(E0[ru]) + bfs(E1[ru]) + bfs(E2[ru]) + bfs(E3[ru]);
        float ie = bfs(E0[ri]) + bfs(E1[ri]) + bfs(E2[ri]) + bfs(E3[ri]);
        float je = bfs(E0[rj]) + bfs(E1[rj]) + bfs(E2[rj]) + bfs(E3[rj]);
        pi = ue * ie;
        pj = ue * je;
        float u0 = eu0[(size_t)user[b] * EMBED + d];
        float i0 = ei0[(size_t)item_i[b] * EMBED + d];
        float j0 = ei0[(size_t)item_j[b] * EMBED + d];
        r = u0 * u0 + i0 * i0 + j0 * j0;
    }
    #pragma unroll
    for (int off = 32; off > 0; off >>= 1) {
        pi += __shfl_down(pi, off);
        pj += __shfl_down(pj, off);
        r  += __shfl_down(r,  off);
    }
    if (d == 0 && b < BATCH) {
        out[b]         = pi * (1.0f / 16.0f);
        out[BATCH + b] = pj * (1.0f / 16.0f);
        rpart[wv] = r;
    }
    __syncthreads();
    if (threadIdx.x == 0)
        rbuf[blockIdx.x] = rpart[0] + rpart[1] + rpart[2] + rpart[3];
}

__global__ void finalize_reg(const float* __restrict__ rbuf, float* __restrict__ out) {
    __shared__ float lds[4];
    int tid = threadIdx.x;
    float s = 0.f;
    for (int i = tid; i < PRED_BLOCKS; i += 256) s += rbuf[i];
    #pragma unroll
    for (int off = 32; off > 0; off >>= 1) s += __shfl_down(s, off);
    if ((tid & 63) == 0) lds[tid >> 6] = s;
    __syncthreads();
    if (tid == 0)
        out[2 * BATCH] = (lds[0] + lds[1] + lds[2] + lds[3]) * (0.5f / (float)BATCH);
}

// ---------------------------------------------------------------------------
extern "C" void kernel_launch(void* const* d_in, const int* in_sizes, int n_in,
                              void* d_out, int out_size, void* d_ws, size_t ws_size,
                              hipStream_t stream) {
    const int*   user      = (const int*)  d_in[0];
    const int*   item_i    = (const int*)  d_in[1];
    const int*   item_j    = (const int*)  d_in[2];
    const int*   edge_src  = (const int*)  d_in[5];
    const int*   edge_dst  = (const int*)  d_in[6];
    const float* edge_vals = (const float*)d_in[7];
    const float* eu0       = (const float*)d_in[8];
    const float* ei0       = (const float*)d_in[9];
    const int    nnz       = in_sizes[5];

    float* out = (float*)d_out;

    // ---- workspace (~96 MB) ----
    ushort* E0    = (ushort*)d_ws;               // 19.2 MB each
    ushort* E1    = E0 + NE;
    ushort* E2    = E1 + NE;
    ushort* E3    = E2 + NE;
    int*    ep    = (int*)(E3 + NE);             // NSB*CAP packed edges, 16.8 MB
    int2*   offs2 = (int2*)(ep + (size_t)NSB * CAP); // {start, deg} per node
    int*    gcur  = (int*)(offs2 + NNODES);      // NSB padded cursors (1/line)
    int*    perm  = gcur + NSB * CSTR;           // NNODES
    float*  rbuf  = (float*)(perm + NNODES);     // PRED_BLOCKS
    // ebuf = NSB*CAP int2 = 33.6 MB: spans E1..E2; dead before gathers write them
    int2*   ebuf  = (int2*)E1;

    const int initBlocks = (int)((NE / 4 + 1023) / 1024);   // 2344

    // 1) fused cursor-init + E0 = bf16(concat)
    init_all<<<1 + initBlocks, 1024, 0, stream>>>(eu0, ei0, E0, gcur);
    // 2) single-pass LDS partition into CAP-padded SB runs (atomic reserve)
    partition2<<<PBLK, 1024, 0, stream>>>(edge_src, edge_dst, edge_vals,
                                          gcur, ebuf, nnz);
    // 3) per-SB node sort: offs2 + packed ep (direct L2-resident scatter) + perm
    sb_sort<<<NSB, 1024, 0, stream>>>(gcur, ebuf, offs2, ep, perm);
    // 4-5) full propagation layers 1-2
    const int gblocks = (int)((((NNODES + 7) / 8) * 64 + 255) / 256);
    gather_E<<<gblocks, 256, 0, stream>>>(offs2, ep, perm, E0, E1);
    gather_E<<<gblocks, 256, 0, stream>>>(offs2, ep, perm, E1, E2);
    // 6) layer 3 directly over batch index arrays (no dedup machinery)
    const int lblocks = (3 * BATCH * 8) / 256;     // 768
    gather_E_list<<<lblocks, 256, 0, stream>>>(offs2, ep, user, item_i, item_j,
                                               E2, E3);
    // 7-8) predictions + reg loss
    predict_kernel<<<PRED_BLOCKS, 256, 0, stream>>>(
        user, item_i, item_j, E0, E1, E2, E3, eu0, ei0, out, rbuf);
    finalize_reg<<<1, 256, 0, stream>>>(rbuf, out);
}